// Round 11
// baseline (185.201 us; speedup 1.0000x reference)
//
#include <hip/hip_runtime.h>

#define NN 4096
#define BB 4

typedef short v8s __attribute__((ext_vector_type(8)));
typedef float v4f __attribute__((ext_vector_type(4)));

__device__ __forceinline__ float bf2f(unsigned short u) {
  union { unsigned int i; float f; } v;
  v.i = ((unsigned int)u) << 16;
  return v.f;
}
__device__ __forceinline__ unsigned short f2bf(float f) {
  union { float f; unsigned int i; } v;
  v.f = f;
  unsigned int r = v.i + 0x7FFFu + ((v.i >> 16) & 1u);
  return (unsigned short)(r >> 16);
}
// pack two f32 -> [bf16(hi):bf16(lo)] by truncation, 1 v_perm_b32
__device__ __forceinline__ unsigned int pkbf(float hi, float lo) {
  union { float f; unsigned int u; } a, b;
  a.f = hi; b.f = lo;
  return __builtin_amdgcn_perm(a.u, b.u, 0x07060302u);
}

__device__ __forceinline__ float ldv(const float* p, size_t i) { return p[i]; }
__device__ __forceinline__ float ldv(const unsigned short* p, size_t i) { return bf2f(p[i]); }

// Per-wave dtype sniff: fp32 data read as bf16 halfwords -> ~23% decode with
// exponent >= 137; bf16 N(0,1) data -> ~none.  Wave-uniform result.
template <int NPL>
__device__ __forceinline__ bool sniff_f32(const unsigned short* xu) {
  const int lane = threadIdx.x & 63;
  int cnt = 0;
  #pragma unroll
  for (int j = 0; j < NPL; j++) {
    unsigned short u = xu[lane * NPL + j];
    cnt += (((u >> 7) & 0xFF) >= 137) ? 1 : 0;
  }
  #pragma unroll
  for (int s = 1; s < 64; s <<= 1) cnt += __shfl_xor(cnt, s);
  return cnt > NPL;
}

// sqrt(log2(e)) folded into q/k projections: energies come out x log2(e),
// so softmax uses raw v_exp_f32 (2^x) with no per-element multiply.
#define QK_SCALE 1.2011224087864498f

// ---------------- Kernel 1: projections via MFMA + LDS staging ----------------
template <typename T>
__device__ __forceinline__ void proj_body(
    const T* __restrict__ x,
    const T* __restrict__ wq2, const T* __restrict__ bq2,
    const T* __restrict__ wq3, const T* __restrict__ bq3,
    const T* __restrict__ wv3, const T* __restrict__ bv3,
    unsigned short* __restrict__ p2bf, unsigned short* __restrict__ p3bf,
    unsigned short* __restrict__ v3bf)
{
  __shared__ unsigned short xt3[64 * 72];   // x3 as [n][c], stride 72
  __shared__ unsigned short xt2[64 * 72];   // x2 as [n][c]
  __shared__ unsigned short wvs[64 * 72];   // wv3 [o][c]
  __shared__ unsigned short wq2s[8 * 72];   // scaled wq2 [o][c]
  __shared__ unsigned short wq3s[8 * 72];

  const int tid  = threadIdx.x;
  const int lane = tid & 63;
  const int w    = tid >> 6;
  const int q    = lane >> 4;
  const int l15  = lane & 15;
  const int bid  = blockIdx.x;
  const int b    = bid >> 6;
  const int nt   = bid & 63;

  #pragma unroll
  for (int i = 0; i < 16; i++) {
    const int idx = tid + i * 256;          // 0..4095
    wvs[(idx >> 6) * 72 + (idx & 63)] = f2bf(ldv(wv3, idx));
  }
  #pragma unroll
  for (int i = 0; i < 4; i++) {
    const int idx = tid + i * 256;          // 0..1023
    if (idx < 512) {
      wq2s[(idx >> 6) * 72 + (idx & 63)] = f2bf(QK_SCALE * ldv(wq2, idx));
    } else {
      const int t2 = idx - 512;
      wq3s[(t2 >> 6) * 72 + (t2 & 63)] = f2bf(QK_SCALE * ldv(wq3, t2));
    }
  }
  const size_t xB = (size_t)b * 128 * NN + ((size_t)nt << 6);
  #pragma unroll
  for (int i = 0; i < 16; i++) {
    const int idx = tid + i * 256;
    const int c = idx >> 6, n = idx & 63;
    xt3[n * 72 + c] = f2bf(ldv(x, xB + (size_t)c * NN + n));
    xt2[n * 72 + c] = f2bf(ldv(x, xB + (size_t)(64 + c) * NN + n));
  }
  __syncthreads();

  const v8s vz = {0, 0, 0, 0, 0, 0, 0, 0};
  v8s aq2[2], aq3[2], av[4][2];
  #pragma unroll
  for (int ks = 0; ks < 2; ks++) {
    const int co = ks * 32 + q * 8;
    aq2[ks] = (l15 < 8) ? *(const v8s*)(wq2s + l15 * 72 + co) : vz;
    aq3[ks] = (l15 < 8) ? *(const v8s*)(wq3s + l15 * 72 + co) : vz;
    #pragma unroll
    for (int t = 0; t < 4; t++)
      av[t][ks] = *(const v8s*)(wvs + (t * 16 + l15) * 72 + co);
  }

  v4f ap2, ap3, avc[4];
  #pragma unroll
  for (int r = 0; r < 4; r++) {
    const int ob = (q < 2) ? q * 4 + r : 0;
    const float b2 = ldv(bq2, ob), b3 = ldv(bq3, ob);
    ap2[r] = (q < 2) ? QK_SCALE * b2 : 0.f;
    ap3[r] = (q < 2) ? QK_SCALE * b3 : 0.f;
  }
  #pragma unroll
  for (int t = 0; t < 4; t++)
    #pragma unroll
    for (int r = 0; r < 4; r++) avc[t][r] = ldv(bv3, t * 16 + q * 4 + r);

  const int nloc = w * 16 + l15;
  #pragma unroll
  for (int ks = 0; ks < 2; ks++) {
    const int co = ks * 32 + q * 8;
    v8s bx2 = *(const v8s*)(xt2 + nloc * 72 + co);
    v8s bx3 = *(const v8s*)(xt3 + nloc * 72 + co);
    ap2 = __builtin_amdgcn_mfma_f32_16x16x32_bf16(aq2[ks], bx2, ap2, 0, 0, 0);
    ap3 = __builtin_amdgcn_mfma_f32_16x16x32_bf16(aq3[ks], bx3, ap3, 0, 0, 0);
    #pragma unroll
    for (int t = 0; t < 4; t++)
      avc[t] = __builtin_amdgcn_mfma_f32_16x16x32_bf16(av[t][ks], bx3, avc[t], 0, 0, 0);
  }

  const int n = (nt << 6) + nloc;
  if (q < 2) {
    uint2 u2, u3;
    u2.x = pkbf(ap2[1], ap2[0]); u2.y = pkbf(ap2[3], ap2[2]);
    u3.x = pkbf(ap3[1], ap3[0]); u3.y = pkbf(ap3[3], ap3[2]);
    *(uint2*)(p2bf + ((size_t)b * NN + n) * 8 + q * 4) = u2;
    *(uint2*)(p3bf + ((size_t)b * NN + n) * 8 + q * 4) = u3;
  }
  #pragma unroll
  for (int t = 0; t < 4; t++)
    #pragma unroll
    for (int r = 0; r < 4; r++)
      v3bf[((size_t)b * 64 + t * 16 + q * 4 + r) * NN + n] = f2bf(avc[t][r]);
}

__global__ __launch_bounds__(256) void proj_kernel(
    const void* __restrict__ x,
    const void* __restrict__ wq2, const void* __restrict__ bq2,
    const void* __restrict__ wq3, const void* __restrict__ bq3,
    const void* __restrict__ wv3, const void* __restrict__ bv3,
    unsigned short* __restrict__ p2bf, unsigned short* __restrict__ p3bf,
    unsigned short* __restrict__ v3bf)
{
  const bool f32 = sniff_f32<16>((const unsigned short*)x);
  if (f32)
    proj_body<float>((const float*)x, (const float*)wq2, (const float*)bq2,
                     (const float*)wq3, (const float*)bq3,
                     (const float*)wv3, (const float*)bv3, p2bf, p3bf, v3bf);
  else
    proj_body<unsigned short>((const unsigned short*)x, (const unsigned short*)wq2,
                              (const unsigned short*)bq2, (const unsigned short*)wq3,
                              (const unsigned short*)bq3, (const unsigned short*)wv3,
                              (const unsigned short*)bv3, p2bf, p3bf, v3bf);
}

// ---------------- Kernel 2: fused dual attention, n-split partials ----------------
// R7 skeleton (single-buffer, 2 barriers/chunk) + ILP restructure: all 8 V
// A-fragments are pulled LDS->registers right after the staging barrier, so the
// LDS pipe overlaps the E-MFMA/exp/pack chain instead of serializing after it.
// E^T by MFMA (x log2e -> raw v_exp_f32); denominators by ones-row MFMA.
__global__ __launch_bounds__(256, 5) void attn_kernel(
    const unsigned short* __restrict__ p2bf, const unsigned short* __restrict__ p3bf,
    const unsigned short* __restrict__ v3bf,
    unsigned short* __restrict__ wso, float* __restrict__ wsl,
    int log2S, int nChunks)
{
  __shared__ unsigned short vtile[64 * 72];        // [c][n], stride 72
  __shared__ unsigned short p2t[64 * 8];           // [n][8]
  __shared__ unsigned short p3t[64 * 8];
  __shared__ unsigned short etile[4][2][16 * 72];  // [wave][mat][m*72 + n]

  const int tid  = threadIdx.x;
  const int lane = tid & 63;
  const int w    = tid >> 6;
  const int q    = lane >> 4;
  const int l15  = lane & 15;
  const int bid  = blockIdx.x;
  const int S    = 1 << log2S;
  const int seg  = bid & (S - 1);
  const int t    = bid >> log2S;
  const int mt   = t & 63;
  const int b    = t >> 6;
  const int m    = (mt << 6) + w * 16 + l15;

  // B-operand for energies: B[k=q*8+j][m=l15]; real k = 0..7 -> quad 0 only.
  v8s b3m = {0, 0, 0, 0, 0, 0, 0, 0};
  if (q == 0) b3m = *(const v8s*)(p3bf + ((size_t)b * NN + m) * 8);

  const v8s ones = {16256, 16256, 16256, 16256, 16256, 16256, 16256, 16256};  // bf16 1.0

  v4f acc32[4], acc33[4], lac2, lac3;
  #pragma unroll
  for (int ct = 0; ct < 4; ct++)
    #pragma unroll
    for (int r = 0; r < 4; r++) { acc32[ct][r] = 0.f; acc33[ct][r] = 0.f; }
  #pragma unroll
  for (int r = 0; r < 4; r++) { lac2[r] = 0.f; lac3[r] = 0.f; }

  const int n_base = seg * (nChunks * 64);
  unsigned short* et2 = &etile[w][0][0];
  unsigned short* et3 = &etile[w][1][0];

  const int vrow = tid >> 3, vseg = tid & 7;
  uint4 vreg0, vreg1, preg;

  // prologue: prefetch chunk 0
  {
    const int n0 = n_base;
    vreg0 = *(const uint4*)(v3bf + ((size_t)b * 64 + vrow) * NN + n0 + vseg * 8);
    vreg1 = *(const uint4*)(v3bf + ((size_t)b * 64 + (vrow + 32)) * NN + n0 + vseg * 8);
    if (tid < 64)       preg = *(const uint4*)(p2bf + ((size_t)b * NN + n0 + tid) * 8);
    else if (tid < 128) preg = *(const uint4*)(p3bf + ((size_t)b * NN + n0 + (tid - 64)) * 8);
  }

  for (int ci = 0; ci < nChunks; ci++) {
    __syncthreads();   // previous chunk's LDS reads done
    *(uint4*)(vtile + vrow * 72 + vseg * 8)        = vreg0;
    *(uint4*)(vtile + (vrow + 32) * 72 + vseg * 8) = vreg1;
    if (tid < 64)       *(uint4*)(p2t + tid * 8)        = preg;
    else if (tid < 128) *(uint4*)(p3t + (tid - 64) * 8) = preg;
    __syncthreads();

    // ---- hoisted V A-fragments: LDS reads overlap the E/exp chain below ----
    v8s va[2][4];
    #pragma unroll
    for (int kh = 0; kh < 2; kh++)
      #pragma unroll
      for (int ct = 0; ct < 4; ct++)
        va[kh][ct] = *(const v8s*)(vtile + (ct * 16 + l15) * 72 + kh * 32 + q * 8);

    // prefetch next chunk's globals (overlaps compute)
    if (ci + 1 < nChunks) {
      const int n1 = n_base + (ci + 1) * 64;
      vreg0 = *(const uint4*)(v3bf + ((size_t)b * 64 + vrow) * NN + n1 + vseg * 8);
      vreg1 = *(const uint4*)(v3bf + ((size_t)b * 64 + (vrow + 32)) * NN + n1 + vseg * 8);
      if (tid < 64)       preg = *(const uint4*)(p2bf + ((size_t)b * NN + n1 + tid) * 8);
      else if (tid < 128) preg = *(const uint4*)(p3bf + ((size_t)b * NN + n1 + (tid - 64)) * 8);
    }

    // energies E^T (x log2e) for 64n x 16m, both matrices
    #pragma unroll
    for (int s = 0; s < 4; s++) {
      v8s A2 = {0, 0, 0, 0, 0, 0, 0, 0};
      v8s A3 = {0, 0, 0, 0, 0, 0, 0, 0};
      if (q == 0) {
        A2 = *(const v8s*)(p2t + (s * 16 + l15) * 8);
        A3 = *(const v8s*)(p3t + (s * 16 + l15) * 8);
      }
      v4f z = {0.f, 0.f, 0.f, 0.f};
      v4f e2 = __builtin_amdgcn_mfma_f32_16x16x32_bf16(A2, b3m, z, 0, 0, 0);
      v4f e3 = __builtin_amdgcn_mfma_f32_16x16x32_bf16(A3, b3m, z, 0, 0, 0);
      float t2[4], t3[4];
      #pragma unroll
      for (int r = 0; r < 4; r++) {
        t2[r] = __builtin_amdgcn_exp2f(e2[r]);   // raw v_exp_f32; |e| bounded
        t3[r] = __builtin_amdgcn_exp2f(e3[r]);
      }
      uint2 w2, w3;
      w2.x = pkbf(t2[1], t2[0]); w2.y = pkbf(t2[3], t2[2]);
      w3.x = pkbf(t3[1], t3[0]); w3.y = pkbf(t3[3], t3[2]);
      *(uint2*)(et2 + l15 * 72 + s * 16 + q * 4) = w2;
      *(uint2*)(et3 + l15 * 72 + s * 16 + q * 4) = w3;
    }

    // PV + denominators (ones-row trick); same-wave LDS RAW, no barrier
    #pragma unroll
    for (int kh = 0; kh < 2; kh++) {
      v8s at2 = *(const v8s*)(et2 + l15 * 72 + kh * 32 + q * 8);
      v8s at3 = *(const v8s*)(et3 + l15 * 72 + kh * 32 + q * 8);
      lac2 = __builtin_amdgcn_mfma_f32_16x16x32_bf16(ones, at2, lac2, 0, 0, 0);
      lac3 = __builtin_amdgcn_mfma_f32_16x16x32_bf16(ones, at3, lac3, 0, 0, 0);
      #pragma unroll
      for (int ct = 0; ct < 4; ct++) {
        acc32[ct] = __builtin_amdgcn_mfma_f32_16x16x32_bf16(va[kh][ct], at2, acc32[ct], 0, 0, 0);
        acc33[ct] = __builtin_amdgcn_mfma_f32_16x16x32_bf16(va[kh][ct], at3, acc33[ct], 0, 0, 0);
      }
    }
  }

  if (q == 0) {
    wsl[((size_t)bid * 2 + 0) * 64 + w * 16 + l15] = lac2[0];
    wsl[((size_t)bid * 2 + 1) * 64 + w * 16 + l15] = lac3[0];
  }
  const int m6 = w * 16 + l15;
  #pragma unroll
  for (int ct = 0; ct < 4; ct++) {
    uint2 o2, o3;
    o2.x = pkbf(acc32[ct][1], acc32[ct][0]); o2.y = pkbf(acc32[ct][3], acc32[ct][2]);
    o3.x = pkbf(acc33[ct][1], acc33[ct][0]); o3.y = pkbf(acc33[ct][3], acc33[ct][2]);
    *(uint2*)(wso + (((size_t)bid * 2 + 0) * 64 + m6) * 64 + ct * 16 + q * 4) = o2;
    *(uint2*)(wso + (((size_t)bid * 2 + 1) * 64 + m6) * 64 + ct * 16 + q * 4) = o3;
  }
}

// ---------------- Kernel 3: reduce partials, normalize, residual ----------------
// 1024 blocks: (b, mt, m-quarter).  Phase 1 lanes along c (coalesced), phase 2
// lanes along m via stride-65 LDS transpose.
__global__ __launch_bounds__(256) void reduce_kernel(
    const unsigned short* __restrict__ wso, const float* __restrict__ wsl,
    const void* __restrict__ x, const void* __restrict__ g2p,
    const void* __restrict__ g3p, void* __restrict__ out, int S)
{
  __shared__ float t32[16 * 65];
  __shared__ float t33[16 * 65];
  __shared__ float iL2s[16], iL3s[16];

  const bool f32 = sniff_f32<4>((const unsigned short*)x);
  const int tid = threadIdx.x;
  const int bid = blockIdx.x;
  const int mq  = bid & 3;
  const int mt  = (bid >> 2) & 63;
  const int b   = bid >> 8;
  const size_t blk0 = (size_t)((b << 6) + mt) * S;

  // phase 1: lanes along c
  const int lr = tid >> 4;            // local m row 0..15
  const int m6 = mq * 16 + lr;
  const int cg = tid & 15;
  {
    float o2[4] = {0.f, 0.f, 0.f, 0.f}, o3[4] = {0.f, 0.f, 0.f, 0.f};
    for (int sg = 0; sg < S; sg++) {
      const uint2 u2 = *(const uint2*)(wso + ((blk0 + sg) * 2 + 0) * 4096 + m6 * 64 + cg * 4);
      const uint2 u3 = *(const uint2*)(wso + ((blk0 + sg) * 2 + 1) * 4096 + m6 * 64 + cg * 4);
      union { unsigned int u; float f; } c0, c1, c2, c3;
      c0.u = u2.x << 16; c1.u = u2.x & 0xFFFF0000u; c2.u = u2.y << 16; c3.u = u2.y & 0xFFFF0000u;
      o2[0] += c0.f; o2[1] += c1.f; o2[2] += c2.f; o2[3] += c3.f;
      c0.u = u3.x << 16; c1.u = u3.x & 0xFFFF0000u; c2.u = u3.y << 16; c3.u = u3.y & 0xFFFF0000u;
      o3[0] += c0.f; o3[1] += c1.f; o3[2] += c2.f; o3[3] += c3.f;
    }
    #pragma unroll
    for (int j = 0; j < 4; j++) {
      t32[lr * 65 + cg * 4 + j] = o2[j];
      t33[lr * 65 + cg * 4 + j] = o3[j];
    }
  }
  if (tid < 16) {
    const int mm = mq * 16 + tid;
    float L2 = 0.f, L3 = 0.f;
    for (int sg = 0; sg < S; sg++) {
      L2 += wsl[((blk0 + sg) * 2 + 0) * 64 + mm];
      L3 += wsl[((blk0 + sg) * 2 + 1) * 64 + mm];
    }
    const float g2 = f32 ? ((const float*)g2p)[0] : bf2f(((const unsigned short*)g2p)[0]);
    const float g3 = f32 ? ((const float*)g3p)[0] : bf2f(((const unsigned short*)g3p)[0]);
    iL2s[tid] = g2 / L2;
    iL3s[tid] = g3 / L3;
  }
  __syncthreads();

  // phase 2: lanes along m (16-wide), 4 c per thread
  const int ml = tid & 15;
  const int cb = tid >> 4;
  const int mg = (mt << 6) + mq * 16 + ml;   // global m
  #pragma unroll
  for (int j = 0; j < 4; j++) {
    const int c = cb * 4 + j;
    const size_t xi = ((size_t)b * 128 + c) * NN + mg;
    const float xv = f32 ? ((const float*)x)[xi] : bf2f(((const unsigned short*)x)[xi]);
    const float val = fmaf(iL2s[ml], t32[ml * 65 + c], fmaf(iL3s[ml], t33[ml * 65 + c], xv));
    const size_t oi = ((size_t)b * 64 + c) * NN + mg;
    if (f32) ((float*)out)[oi] = val;
    else     ((unsigned short*)out)[oi] = f2bf(val);
  }
}

extern "C" void kernel_launch(void* const* d_in, const int* in_sizes, int n_in,
                              void* d_out, int out_size, void* d_ws, size_t ws_size,
                              hipStream_t stream) {
  const void* x   = d_in[0];
  const void* wq2 = d_in[1];
  const void* bq2 = d_in[2];
  const void* wq3 = d_in[3];
  const void* bq3 = d_in[4];
  const void* wv3 = d_in[5];
  const void* bv3 = d_in[6];
  const void* g2  = d_in[7];
  const void* g3  = d_in[8];

  unsigned short* p2bf = (unsigned short*)d_ws;
  unsigned short* p3bf = p2bf + (size_t)BB * NN * 8;
  unsigned short* v3bf = p3bf + (size_t)BB * NN * 8;
  const size_t base = 2 * (size_t)BB * NN * 8 * 2 + (size_t)BB * 64 * NN * 2;  // 2.5 MB

  const size_t per_blk = 512 + 16384;
  int S = 1, log2S = 0;
  if      (ws_size >= base + (size_t)256 * 8 * per_blk) { S = 8; log2S = 3; }
  else if (ws_size >= base + (size_t)256 * 4 * per_blk) { S = 4; log2S = 2; }
  else if (ws_size >= base + (size_t)256 * 2 * per_blk) { S = 2; log2S = 1; }

  float* wsl = (float*)((char*)d_ws + base);
  unsigned short* wso = (unsigned short*)((char*)wsl + (size_t)256 * S * 512);
  const int nChunks = 64 / S;

  proj_kernel<<<dim3(BB * 64), dim3(256), 0, stream>>>(
      x, wq2, bq2, wq3, bq3, wv3, bv3, p2bf, p3bf, v3bf);
  attn_kernel<<<dim3(BB * 64 * S), dim3(256), 0, stream>>>(
      p2bf, p3bf, v3bf, wso, wsl, log2S, nChunks);
  reduce_kernel<<<dim3(BB * 64 * 4), dim3(256), 0, stream>>>(
      wso, wsl, x, g2, g3, d_out, S);
}

// Round 12
// 126.200 us; speedup vs baseline: 1.4675x; 1.4675x over previous
//
#include <hip/hip_runtime.h>

#define NN 4096
#define BB 4

typedef short v8s __attribute__((ext_vector_type(8)));
typedef float v4f __attribute__((ext_vector_type(4)));

__device__ __forceinline__ float bf2f(unsigned short u) {
  union { unsigned int i; float f; } v;
  v.i = ((unsigned int)u) << 16;
  return v.f;
}
__device__ __forceinline__ unsigned short f2bf(float f) {
  union { float f; unsigned int i; } v;
  v.f = f;
  unsigned int r = v.i + 0x7FFFu + ((v.i >> 16) & 1u);
  return (unsigned short)(r >> 16);
}
// pack two f32 -> [bf16(hi):bf16(lo)] by truncation, 1 v_perm_b32
__device__ __forceinline__ unsigned int pkbf(float hi, float lo) {
  union { float f; unsigned int u; } a, b;
  a.f = hi; b.f = lo;
  return __builtin_amdgcn_perm(a.u, b.u, 0x07060302u);
}

__device__ __forceinline__ float ldv(const float* p, size_t i) { return p[i]; }
__device__ __forceinline__ float ldv(const unsigned short* p, size_t i) { return bf2f(p[i]); }

// Per-wave dtype sniff: fp32 data read as bf16 halfwords -> ~23% decode with
// exponent >= 137; bf16 N(0,1) data -> ~none.  Wave-uniform result.
template <int NPL>
__device__ __forceinline__ bool sniff_f32(const unsigned short* xu) {
  const int lane = threadIdx.x & 63;
  int cnt = 0;
  #pragma unroll
  for (int j = 0; j < NPL; j++) {
    unsigned short u = xu[lane * NPL + j];
    cnt += (((u >> 7) & 0xFF) >= 137) ? 1 : 0;
  }
  #pragma unroll
  for (int s = 1; s < 64; s <<= 1) cnt += __shfl_xor(cnt, s);
  return cnt > NPL;
}

// sqrt(log2(e)) folded into q/k projections: energies come out x log2(e),
// so softmax uses raw v_exp_f32 (2^x) with no per-element multiply.
#define QK_SCALE 1.2011224087864498f

// ---------------- Kernel 1: projections via MFMA + LDS staging ----------------
template <typename T>
__device__ __forceinline__ void proj_body(
    const T* __restrict__ x,
    const T* __restrict__ wq2, const T* __restrict__ bq2,
    const T* __restrict__ wq3, const T* __restrict__ bq3,
    const T* __restrict__ wv3, const T* __restrict__ bv3,
    unsigned short* __restrict__ p2bf, unsigned short* __restrict__ p3bf,
    unsigned short* __restrict__ v3bf)
{
  __shared__ unsigned short xt3[64 * 72];   // x3 as [n][c], stride 72
  __shared__ unsigned short xt2[64 * 72];   // x2 as [n][c]
  __shared__ unsigned short wvs[64 * 72];   // wv3 [o][c]
  __shared__ unsigned short wq2s[8 * 72];   // scaled wq2 [o][c]
  __shared__ unsigned short wq3s[8 * 72];

  const int tid  = threadIdx.x;
  const int lane = tid & 63;
  const int w    = tid >> 6;
  const int q    = lane >> 4;
  const int l15  = lane & 15;
  const int bid  = blockIdx.x;
  const int b    = bid >> 6;
  const int nt   = bid & 63;

  #pragma unroll
  for (int i = 0; i < 16; i++) {
    const int idx = tid + i * 256;          // 0..4095
    wvs[(idx >> 6) * 72 + (idx & 63)] = f2bf(ldv(wv3, idx));
  }
  #pragma unroll
  for (int i = 0; i < 4; i++) {
    const int idx = tid + i * 256;          // 0..1023
    if (idx < 512) {
      wq2s[(idx >> 6) * 72 + (idx & 63)] = f2bf(QK_SCALE * ldv(wq2, idx));
    } else {
      const int t2 = idx - 512;
      wq3s[(t2 >> 6) * 72 + (t2 & 63)] = f2bf(QK_SCALE * ldv(wq3, t2));
    }
  }
  const size_t xB = (size_t)b * 128 * NN + ((size_t)nt << 6);
  #pragma unroll
  for (int i = 0; i < 16; i++) {
    const int idx = tid + i * 256;
    const int c = idx >> 6, n = idx & 63;
    xt3[n * 72 + c] = f2bf(ldv(x, xB + (size_t)c * NN + n));
    xt2[n * 72 + c] = f2bf(ldv(x, xB + (size_t)(64 + c) * NN + n));
  }
  __syncthreads();

  const v8s vz = {0, 0, 0, 0, 0, 0, 0, 0};
  v8s aq2[2], aq3[2], av[4][2];
  #pragma unroll
  for (int ks = 0; ks < 2; ks++) {
    const int co = ks * 32 + q * 8;
    aq2[ks] = (l15 < 8) ? *(const v8s*)(wq2s + l15 * 72 + co) : vz;
    aq3[ks] = (l15 < 8) ? *(const v8s*)(wq3s + l15 * 72 + co) : vz;
    #pragma unroll
    for (int t = 0; t < 4; t++)
      av[t][ks] = *(const v8s*)(wvs + (t * 16 + l15) * 72 + co);
  }

  v4f ap2, ap3, avc[4];
  #pragma unroll
  for (int r = 0; r < 4; r++) {
    const int ob = (q < 2) ? q * 4 + r : 0;
    const float b2 = ldv(bq2, ob), b3 = ldv(bq3, ob);
    ap2[r] = (q < 2) ? QK_SCALE * b2 : 0.f;
    ap3[r] = (q < 2) ? QK_SCALE * b3 : 0.f;
  }
  #pragma unroll
  for (int t = 0; t < 4; t++)
    #pragma unroll
    for (int r = 0; r < 4; r++) avc[t][r] = ldv(bv3, t * 16 + q * 4 + r);

  const int nloc = w * 16 + l15;
  #pragma unroll
  for (int ks = 0; ks < 2; ks++) {
    const int co = ks * 32 + q * 8;
    v8s bx2 = *(const v8s*)(xt2 + nloc * 72 + co);
    v8s bx3 = *(const v8s*)(xt3 + nloc * 72 + co);
    ap2 = __builtin_amdgcn_mfma_f32_16x16x32_bf16(aq2[ks], bx2, ap2, 0, 0, 0);
    ap3 = __builtin_amdgcn_mfma_f32_16x16x32_bf16(aq3[ks], bx3, ap3, 0, 0, 0);
    #pragma unroll
    for (int t = 0; t < 4; t++)
      avc[t] = __builtin_amdgcn_mfma_f32_16x16x32_bf16(av[t][ks], bx3, avc[t], 0, 0, 0);
  }

  const int n = (nt << 6) + nloc;
  if (q < 2) {
    uint2 u2, u3;
    u2.x = pkbf(ap2[1], ap2[0]); u2.y = pkbf(ap2[3], ap2[2]);
    u3.x = pkbf(ap3[1], ap3[0]); u3.y = pkbf(ap3[3], ap3[2]);
    *(uint2*)(p2bf + ((size_t)b * NN + n) * 8 + q * 4) = u2;
    *(uint2*)(p3bf + ((size_t)b * NN + n) * 8 + q * 4) = u3;
  }
  #pragma unroll
  for (int t = 0; t < 4; t++)
    #pragma unroll
    for (int r = 0; r < 4; r++)
      v3bf[((size_t)b * 64 + t * 16 + q * 4 + r) * NN + n] = f2bf(avc[t][r]);
}

__global__ __launch_bounds__(256) void proj_kernel(
    const void* __restrict__ x,
    const void* __restrict__ wq2, const void* __restrict__ bq2,
    const void* __restrict__ wq3, const void* __restrict__ bq3,
    const void* __restrict__ wv3, const void* __restrict__ bv3,
    unsigned short* __restrict__ p2bf, unsigned short* __restrict__ p3bf,
    unsigned short* __restrict__ v3bf)
{
  const bool f32 = sniff_f32<16>((const unsigned short*)x);
  if (f32)
    proj_body<float>((const float*)x, (const float*)wq2, (const float*)bq2,
                     (const float*)wq3, (const float*)bq3,
                     (const float*)wv3, (const float*)bv3, p2bf, p3bf, v3bf);
  else
    proj_body<unsigned short>((const unsigned short*)x, (const unsigned short*)wq2,
                              (const unsigned short*)bq2, (const unsigned short*)wq3,
                              (const unsigned short*)bq3, (const unsigned short*)wv3,
                              (const unsigned short*)bv3, p2bf, p3bf, v3bf);
}

// ---------------- Kernel 2: fused dual attention, n-split partials ----------------
// R7 structure (best measured: 45.2 us).  E^T by MFMA (x log2e -> raw
// v_exp_f32), denominators by ones-row MFMA, single-buffer LDS staging with
// register prefetch, 2 barriers/chunk.  NOTE: R8 (8-wave), R10 (dbuf/1-barrier),
// R11 (va-hoist ILP) all measured neutral or worse — do not re-try without
// new counter evidence.
__global__ __launch_bounds__(256, 4) void attn_kernel(
    const unsigned short* __restrict__ p2bf, const unsigned short* __restrict__ p3bf,
    const unsigned short* __restrict__ v3bf,
    unsigned short* __restrict__ wso, float* __restrict__ wsl,
    int log2S, int nChunks)
{
  __shared__ unsigned short vtile[64 * 72];        // [c][n], stride 72
  __shared__ unsigned short p2t[64 * 8];           // [n][8]
  __shared__ unsigned short p3t[64 * 8];
  __shared__ unsigned short etile[4][2][16 * 72];  // [wave][mat][m*72 + n]

  const int tid  = threadIdx.x;
  const int lane = tid & 63;
  const int w    = tid >> 6;
  const int q    = lane >> 4;
  const int l15  = lane & 15;
  const int bid  = blockIdx.x;
  const int S    = 1 << log2S;
  const int seg  = bid & (S - 1);
  const int t    = bid >> log2S;
  const int mt   = t & 63;
  const int b    = t >> 6;
  const int m    = (mt << 6) + w * 16 + l15;

  // B-operand for energies: B[k=q*8+j][m=l15]; real k = 0..7 -> quad 0 only.
  v8s b3m = {0, 0, 0, 0, 0, 0, 0, 0};
  if (q == 0) b3m = *(const v8s*)(p3bf + ((size_t)b * NN + m) * 8);

  const v8s ones = {16256, 16256, 16256, 16256, 16256, 16256, 16256, 16256};  // bf16 1.0

  v4f acc32[4], acc33[4], lac2, lac3;
  #pragma unroll
  for (int ct = 0; ct < 4; ct++)
    #pragma unroll
    for (int r = 0; r < 4; r++) { acc32[ct][r] = 0.f; acc33[ct][r] = 0.f; }
  #pragma unroll
  for (int r = 0; r < 4; r++) { lac2[r] = 0.f; lac3[r] = 0.f; }

  const int n_base = seg * (nChunks * 64);
  unsigned short* et2 = &etile[w][0][0];
  unsigned short* et3 = &etile[w][1][0];

  const int vrow = tid >> 3, vseg = tid & 7;
  uint4 vreg0, vreg1, preg;

  {
    const int n0 = n_base;
    vreg0 = *(const uint4*)(v3bf + ((size_t)b * 64 + vrow) * NN + n0 + vseg * 8);
    vreg1 = *(const uint4*)(v3bf + ((size_t)b * 64 + (vrow + 32)) * NN + n0 + vseg * 8);
    if (tid < 64)       preg = *(const uint4*)(p2bf + ((size_t)b * NN + n0 + tid) * 8);
    else if (tid < 128) preg = *(const uint4*)(p3bf + ((size_t)b * NN + n0 + (tid - 64)) * 8);
  }

  for (int ci = 0; ci < nChunks; ci++) {
    __syncthreads();
    *(uint4*)(vtile + vrow * 72 + vseg * 8)        = vreg0;
    *(uint4*)(vtile + (vrow + 32) * 72 + vseg * 8) = vreg1;
    if (tid < 64)       *(uint4*)(p2t + tid * 8)        = preg;
    else if (tid < 128) *(uint4*)(p3t + (tid - 64) * 8) = preg;
    __syncthreads();

    if (ci + 1 < nChunks) {
      const int n1 = n_base + (ci + 1) * 64;
      vreg0 = *(const uint4*)(v3bf + ((size_t)b * 64 + vrow) * NN + n1 + vseg * 8);
      vreg1 = *(const uint4*)(v3bf + ((size_t)b * 64 + (vrow + 32)) * NN + n1 + vseg * 8);
      if (tid < 64)       preg = *(const uint4*)(p2bf + ((size_t)b * NN + n1 + tid) * 8);
      else if (tid < 128) preg = *(const uint4*)(p3bf + ((size_t)b * NN + n1 + (tid - 64)) * 8);
    }

    // energies E^T (x log2e) for 64n x 16m, both matrices
    #pragma unroll
    for (int s = 0; s < 4; s++) {
      v8s A2 = {0, 0, 0, 0, 0, 0, 0, 0};
      v8s A3 = {0, 0, 0, 0, 0, 0, 0, 0};
      if (q == 0) {
        A2 = *(const v8s*)(p2t + (s * 16 + l15) * 8);
        A3 = *(const v8s*)(p3t + (s * 16 + l15) * 8);
      }
      v4f z = {0.f, 0.f, 0.f, 0.f};
      v4f e2 = __builtin_amdgcn_mfma_f32_16x16x32_bf16(A2, b3m, z, 0, 0, 0);
      v4f e3 = __builtin_amdgcn_mfma_f32_16x16x32_bf16(A3, b3m, z, 0, 0, 0);
      float t2[4], t3[4];
      #pragma unroll
      for (int r = 0; r < 4; r++) {
        t2[r] = __builtin_amdgcn_exp2f(e2[r]);   // raw v_exp_f32; |e| bounded
        t3[r] = __builtin_amdgcn_exp2f(e3[r]);
      }
      uint2 w2, w3;
      w2.x = pkbf(t2[1], t2[0]); w2.y = pkbf(t2[3], t2[2]);
      w3.x = pkbf(t3[1], t3[0]); w3.y = pkbf(t3[3], t3[2]);
      *(uint2*)(et2 + l15 * 72 + s * 16 + q * 4) = w2;
      *(uint2*)(et3 + l15 * 72 + s * 16 + q * 4) = w3;
    }

    // PV + denominators (ones-row trick); same-wave LDS RAW, no barrier
    #pragma unroll
    for (int kh = 0; kh < 2; kh++) {
      v8s at2 = *(const v8s*)(et2 + l15 * 72 + kh * 32 + q * 8);
      v8s at3 = *(const v8s*)(et3 + l15 * 72 + kh * 32 + q * 8);
      lac2 = __builtin_amdgcn_mfma_f32_16x16x32_bf16(ones, at2, lac2, 0, 0, 0);
      lac3 = __builtin_amdgcn_mfma_f32_16x16x32_bf16(ones, at3, lac3, 0, 0, 0);
      #pragma unroll
      for (int ct = 0; ct < 4; ct++) {
        v8s va = *(const v8s*)(vtile + (ct * 16 + l15) * 72 + kh * 32 + q * 8);
        acc32[ct] = __builtin_amdgcn_mfma_f32_16x16x32_bf16(va, at2, acc32[ct], 0, 0, 0);
        acc33[ct] = __builtin_amdgcn_mfma_f32_16x16x32_bf16(va, at3, acc33[ct], 0, 0, 0);
      }
    }
  }

  if (q == 0) {
    wsl[((size_t)bid * 2 + 0) * 64 + w * 16 + l15] = lac2[0];
    wsl[((size_t)bid * 2 + 1) * 64 + w * 16 + l15] = lac3[0];
  }
  const int m6 = w * 16 + l15;
  #pragma unroll
  for (int ct = 0; ct < 4; ct++) {
    uint2 o2, o3;
    o2.x = pkbf(acc32[ct][1], acc32[ct][0]); o2.y = pkbf(acc32[ct][3], acc32[ct][2]);
    o3.x = pkbf(acc33[ct][1], acc33[ct][0]); o3.y = pkbf(acc33[ct][3], acc33[ct][2]);
    *(uint2*)(wso + (((size_t)bid * 2 + 0) * 64 + m6) * 64 + ct * 16 + q * 4) = o2;
    *(uint2*)(wso + (((size_t)bid * 2 + 1) * 64 + m6) * 64 + ct * 16 + q * 4) = o3;
  }
}

// ---------------- Kernel 3: reduce partials, normalize, residual ----------------
// 1024 blocks: (b, mt, m-quarter).  Phase 1 lanes along c (coalesced), phase 2
// lanes along m via stride-65 LDS transpose.
__global__ __launch_bounds__(256) void reduce_kernel(
    const unsigned short* __restrict__ wso, const float* __restrict__ wsl,
    const void* __restrict__ x, const void* __restrict__ g2p,
    const void* __restrict__ g3p, void* __restrict__ out, int S)
{
  __shared__ float t32[16 * 65];
  __shared__ float t33[16 * 65];
  __shared__ float iL2s[16], iL3s[16];

  const bool f32 = sniff_f32<4>((const unsigned short*)x);
  const int tid = threadIdx.x;
  const int bid = blockIdx.x;
  const int mq  = bid & 3;
  const int mt  = (bid >> 2) & 63;
  const int b   = bid >> 8;
  const size_t blk0 = (size_t)((b << 6) + mt) * S;

  // phase 1: lanes along c
  const int lr = tid >> 4;            // local m row 0..15
  const int m6 = mq * 16 + lr;
  const int cg = tid & 15;
  {
    float o2[4] = {0.f, 0.f, 0.f, 0.f}, o3[4] = {0.f, 0.f, 0.f, 0.f};
    for (int sg = 0; sg < S; sg++) {
      const uint2 u2 = *(const uint2*)(wso + ((blk0 + sg) * 2 + 0) * 4096 + m6 * 64 + cg * 4);
      const uint2 u3 = *(const uint2*)(wso + ((blk0 + sg) * 2 + 1) * 4096 + m6 * 64 + cg * 4);
      union { unsigned int u; float f; } c0, c1, c2, c3;
      c0.u = u2.x << 16; c1.u = u2.x & 0xFFFF0000u; c2.u = u2.y << 16; c3.u = u2.y & 0xFFFF0000u;
      o2[0] += c0.f; o2[1] += c1.f; o2[2] += c2.f; o2[3] += c3.f;
      c0.u = u3.x << 16; c1.u = u3.x & 0xFFFF0000u; c2.u = u3.y << 16; c3.u = u3.y & 0xFFFF0000u;
      o3[0] += c0.f; o3[1] += c1.f; o3[2] += c2.f; o3[3] += c3.f;
    }
    #pragma unroll
    for (int j = 0; j < 4; j++) {
      t32[lr * 65 + cg * 4 + j] = o2[j];
      t33[lr * 65 + cg * 4 + j] = o3[j];
    }
  }
  if (tid < 16) {
    const int mm = mq * 16 + tid;
    float L2 = 0.f, L3 = 0.f;
    for (int sg = 0; sg < S; sg++) {
      L2 += wsl[((blk0 + sg) * 2 + 0) * 64 + mm];
      L3 += wsl[((blk0 + sg) * 2 + 1) * 64 + mm];
    }
    const float g2 = f32 ? ((const float*)g2p)[0] : bf2f(((const unsigned short*)g2p)[0]);
    const float g3 = f32 ? ((const float*)g3p)[0] : bf2f(((const unsigned short*)g3p)[0]);
    iL2s[tid] = g2 / L2;
    iL3s[tid] = g3 / L3;
  }
  __syncthreads();

  // phase 2: lanes along m (16-wide), 4 c per thread
  const int ml = tid & 15;
  const int cb = tid >> 4;
  const int mg = (mt << 6) + mq * 16 + ml;   // global m
  #pragma unroll
  for (int j = 0; j < 4; j++) {
    const int c = cb * 4 + j;
    const size_t xi = ((size_t)b * 128 + c) * NN + mg;
    const float xv = f32 ? ((const float*)x)[xi] : bf2f(((const unsigned short*)x)[xi]);
    const float val = fmaf(iL2s[ml], t32[ml * 65 + c], fmaf(iL3s[ml], t33[ml * 65 + c], xv));
    const size_t oi = ((size_t)b * 64 + c) * NN + mg;
    if (f32) ((float*)out)[oi] = val;
    else     ((unsigned short*)out)[oi] = f2bf(val);
  }
}

extern "C" void kernel_launch(void* const* d_in, const int* in_sizes, int n_in,
                              void* d_out, int out_size, void* d_ws, size_t ws_size,
                              hipStream_t stream) {
  const void* x   = d_in[0];
  const void* wq2 = d_in[1];
  const void* bq2 = d_in[2];
  const void* wq3 = d_in[3];
  const void* bq3 = d_in[4];
  const void* wv3 = d_in[5];
  const void* bv3 = d_in[6];
  const void* g2  = d_in[7];
  const void* g3  = d_in[8];

  unsigned short* p2bf = (unsigned short*)d_ws;
  unsigned short* p3bf = p2bf + (size_t)BB * NN * 8;
  unsigned short* v3bf = p3bf + (size_t)BB * NN * 8;
  const size_t base = 2 * (size_t)BB * NN * 8 * 2 + (size_t)BB * 64 * NN * 2;  // 2.5 MB

  const size_t per_blk = 512 + 16384;
  int S = 1, log2S = 0;
  if      (ws_size >= base + (size_t)256 * 8 * per_blk) { S = 8; log2S = 3; }
  else if (ws_size >= base + (size_t)256 * 4 * per_blk) { S = 4; log2S = 2; }
  else if (ws_size >= base + (size_t)256 * 2 * per_blk) { S = 2; log2S = 1; }

  float* wsl = (float*)((char*)d_ws + base);
  unsigned short* wso = (unsigned short*)((char*)wsl + (size_t)256 * S * 512);
  const int nChunks = 64 / S;

  proj_kernel<<<dim3(BB * 64), dim3(256), 0, stream>>>(
      x, wq2, bq2, wq3, bq3, wv3, bv3, p2bf, p3bf, v3bf);
  attn_kernel<<<dim3(BB * 64 * S), dim3(256), 0, stream>>>(
      p2bf, p3bf, v3bf, wso, wsl, log2S, nChunks);
  reduce_kernel<<<dim3(BB * 64 * 4), dim3(256), 0, stream>>>(
      wso, wsl, x, g2, g3, d_out, S);
}